// Round 7
// baseline (191.596 us; speedup 1.0000x reference)
//
#include <hip/hip_runtime.h>
#include <hip/hip_bf16.h>
#include <math.h>

// Problem constants
constexpr int Bb = 32;
constexpr int Ll = 1024;
constexpr int DC = 1024;
constexpr int DQ = 1024;
constexpr int Hh = 512;
#define NEG_NUM -10000.0f

typedef __attribute__((ext_vector_type(8))) short bf16x8;
typedef __attribute__((ext_vector_type(4))) float f32x4;

#define GLOAD_LDS16(g, l)                                                  \
    __builtin_amdgcn_global_load_lds(                                      \
        (const __attribute__((address_space(1))) void*)(g),                \
        (__attribute__((address_space(3))) void*)(l), 16, 0, 0)

__device__ inline unsigned short f2bf(float f) {           // RNE f32->bf16
    unsigned int x = __float_as_uint(f);
    unsigned int r = (x + 0x7FFFu + ((x >> 16) & 1u)) >> 16;
    return (unsigned short)r;
}

// ---------------------------------------------------------------------------
// prep, 2432 blocks:
//   [0,2048):    W1[:DC] (1024x512) -> w1t bf16 (512x1024 transposed)
//   [2048,2176): zero out_ctx AND score (32768 floats each)
//   [2176,2432): qb[b,h] = query[b,:] @ W1[DC:,h] + b1[h]
// ---------------------------------------------------------------------------
__global__ __launch_bounds__(256) void prep_kernel(const float* __restrict__ W1,
                                                   const float* __restrict__ query,
                                                   const float* __restrict__ b1,
                                                   unsigned short* __restrict__ w1t,
                                                   float* __restrict__ qb,
                                                   float* __restrict__ score,
                                                   float* __restrict__ out_ctx) {
    __shared__ float red[4][64];
    const int bid = blockIdx.x;
    if (bid < 2048) {
        int idx = bid * 256 + threadIdx.x;   // n*1024 + k
        int n = idx >> 10, k = idx & 1023;
        w1t[idx] = f2bf(W1[(size_t)k * Hh + n]);
    } else if (bid < 2176) {
        int i = (bid - 2048) * 256 + threadIdx.x;
        out_ctx[i] = 0.f;
        score[i] = 0.f;
    } else {
        const int qbid = bid - 2176;          // 0..255
        const int b  = qbid >> 3;
        const int hg = qbid & 7;
        const int hl = threadIdx.x & 63;
        const int j  = threadIdx.x >> 6;
        const int h  = hg * 64 + hl;
        const float* q = query + (size_t)b * DQ + j * 256;
        const float* w = W1 + (size_t)(DC + j * 256) * Hh + h;
        float a0 = 0.f, a1 = 0.f, a2 = 0.f, a3 = 0.f;
#pragma unroll 4
        for (int c = 0; c < 256; c += 4) {
            a0 += q[c + 0] * w[(size_t)(c + 0) * Hh];
            a1 += q[c + 1] * w[(size_t)(c + 1) * Hh];
            a2 += q[c + 2] * w[(size_t)(c + 2) * Hh];
            a3 += q[c + 3] * w[(size_t)(c + 3) * Hh];
        }
        red[j][hl] = (a0 + a1) + (a2 + a3);
        __syncthreads();
        if (j == 0)
            qb[(size_t)b * Hh + h] = red[0][hl] + red[1][hl] + red[2][hl] + red[3][hl] + b1[h];
    }
}

// ---------------------------------------------------------------------------
// Fused MFMA GEMM + tanh + w2 reduction — A direct global->reg (no LDS).
//   BM=128, BN=128, BK=32, 256 thr / 4 waves (2x2), acc 4x4 per wave.
//   A fragment = 8 contiguous fp32 at (row, k0+lk*8): 2 x float4 global loads
//     per frag, issued at iteration top, cvt'd to bf16 AFTER the barrier
//     (loads get the whole ds_read+MFMA window to land). 8x read dup is
//     L2-served (2 waves/block x 4 sibling n-blocks on same XCD).
//   B staged bf16 via fire-and-forget global_load_lds, double-buffered
//     (16 KB LDS total), one __syncthreads per K-step.
//   Epilogue: score[row] += sum_col tanh(acc + qb[col]) * w2[col] (atomicAdd).
// ---------------------------------------------------------------------------
__global__ __launch_bounds__(256) void gemm_fused(const float* __restrict__ ctx,
                                                  const unsigned short* __restrict__ w1t,
                                                  const float* __restrict__ qb,
                                                  const float* __restrict__ w2,
                                                  float* __restrict__ score) {
    __shared__ unsigned short Bs[2][128 * 32];   // 2 x 8 KB, [n][64B k-row]

    const int m0 = blockIdx.x * 128;
    const int n0 = blockIdx.y * 128;
    const int tid = threadIdx.x;
    const int w = tid >> 6, lane = tid & 63;
    const int wr = w >> 1, wc = w & 1;
    const int lr = lane & 15, lk = lane >> 4;
    const int brow = lane >> 2, bcolb = (lane & 3) * 16;  // B staging coords

    char* BsB = (char*)Bs;
    const char* w1tB = (const char*)w1t;

    // This lane's A base: row (m0 + wr*64 + mf*16 + lr), k-slot lk*8
    const float* agbase = ctx + (size_t)(m0 + wr * 64 + lr) * DC + lk * 8;

    f32x4 acc[4][4];
#pragma unroll
    for (int mf = 0; mf < 4; ++mf)
#pragma unroll
        for (int nf = 0; nf < 4; ++nf) acc[mf][nf] = (f32x4){0.f, 0.f, 0.f, 0.f};

    float4 ra[8];        // in-flight A fp32 (4 frags x 32 B)
    bf16x8 a[4];         // cvt'd A fragments for the current step

    // ---- prologue: stage B(0) into buf0, load A(0) ----
#pragma unroll
    for (int i = 0; i < 2; ++i) {
        int chunk = w * 2 + i;                     // 8 chunks x 1 KB
        GLOAD_LDS16(w1tB + (size_t)(n0 + chunk * 16 + brow) * 2048 + bcolb,
                    BsB + chunk * 1024);
    }
#pragma unroll
    for (int mf = 0; mf < 4; ++mf) {
        const float* ag = agbase + (size_t)mf * 16 * DC;
        ra[mf * 2 + 0] = *(const float4*)(ag + 0);
        ra[mf * 2 + 1] = *(const float4*)(ag + 4);
    }
    __syncthreads();                               // drains B(0) + A(0)
#pragma unroll
    for (int mf = 0; mf < 4; ++mf) {
        union { unsigned short us[8]; bf16x8 v; } pk;
        float4 f0 = ra[mf * 2 + 0], f1 = ra[mf * 2 + 1];
        pk.us[0] = f2bf(f0.x); pk.us[1] = f2bf(f0.y); pk.us[2] = f2bf(f0.z); pk.us[3] = f2bf(f0.w);
        pk.us[4] = f2bf(f1.x); pk.us[5] = f2bf(f1.y); pk.us[6] = f2bf(f1.z); pk.us[7] = f2bf(f1.w);
        a[mf] = pk.v;
    }

    // ---- main loop: 32 K-steps, one barrier each ----
    for (int ks = 0; ks < 32; ++ks) {
        const int cur = ks & 1;
        const bool pf = (ks < 31);
        if (pf) {
            const int k1 = (ks + 1) * 32;
            // next B tile: fire-and-forget -> LDS[nxt]
#pragma unroll
            for (int i = 0; i < 2; ++i) {
                int chunk = w * 2 + i;
                GLOAD_LDS16(w1tB + (size_t)(n0 + chunk * 16 + brow) * 2048 + k1 * 2 + bcolb,
                            BsB + (cur ^ 1) * 8192 + chunk * 1024);
            }
            // next A fragments: global -> regs (drain at end-of-step barrier)
#pragma unroll
            for (int mf = 0; mf < 4; ++mf) {
                const float* ag = agbase + (size_t)mf * 16 * DC + k1;
                ra[mf * 2 + 0] = *(const float4*)(ag + 0);
                ra[mf * 2 + 1] = *(const float4*)(ag + 4);
            }
        }

        // compute current: 4 ds_read_b128 (B only) + 16 MFMA from regs
        const char* Bc = BsB + cur * 8192 + (wc * 64 + lr) * 64 + lk * 16;
        bf16x8 bb[4];
#pragma unroll
        for (int nf = 0; nf < 4; ++nf) bb[nf] = *(const bf16x8*)(Bc + nf * 1024);
#pragma unroll
        for (int mf = 0; mf < 4; ++mf)
#pragma unroll
            for (int nf = 0; nf < 4; ++nf)
                acc[mf][nf] = __builtin_amdgcn_mfma_f32_16x16x32_bf16(a[mf], bb[nf], acc[mf][nf], 0, 0, 0);

        __syncthreads();   // drains B(k+1) into LDS and A(k+1) into regs

        if (pf) {
#pragma unroll
            for (int mf = 0; mf < 4; ++mf) {
                union { unsigned short us[8]; bf16x8 v; } pk;
                float4 f0 = ra[mf * 2 + 0], f1 = ra[mf * 2 + 1];
                pk.us[0] = f2bf(f0.x); pk.us[1] = f2bf(f0.y); pk.us[2] = f2bf(f0.z); pk.us[3] = f2bf(f0.w);
                pk.us[4] = f2bf(f1.x); pk.us[5] = f2bf(f1.y); pk.us[6] = f2bf(f1.z); pk.us[7] = f2bf(f1.w);
                a[mf] = pk.v;
            }
        }
    }

    // ---- epilogue: score[row] += sum_col tanh(acc + qb[col]) * w2[col] ----
    // C/D layout: col = n0 + wc*64 + nf*16 + lr, row = m0 + wr*64 + mf*16 + lk*4 + r.
    const int bq = m0 >> 10;                     // 128 | 1024 -> one batch per block
    const float* qbb = qb + (size_t)bq * Hh;
#pragma unroll
    for (int mf = 0; mf < 4; ++mf) {
        float s0 = 0.f, s1 = 0.f, s2 = 0.f, s3 = 0.f;
#pragma unroll
        for (int nf = 0; nf < 4; ++nf) {
            int col = n0 + wc * 64 + nf * 16 + lr;
            float wv = w2[col];
            float qv = qbb[col];
            s0 += tanhf(acc[mf][nf][0] + qv) * wv;
            s1 += tanhf(acc[mf][nf][1] + qv) * wv;
            s2 += tanhf(acc[mf][nf][2] + qv) * wv;
            s3 += tanhf(acc[mf][nf][3] + qv) * wv;
        }
#pragma unroll
        for (int off = 8; off; off >>= 1) {
            s0 += __shfl_xor(s0, off, 16);
            s1 += __shfl_xor(s1, off, 16);
            s2 += __shfl_xor(s2, off, 16);
            s3 += __shfl_xor(s3, off, 16);
        }
        if (lr == 0) {
            int row = m0 + wr * 64 + mf * 16 + lk * 4;
            atomicAdd(&score[row + 0], s0);
            atomicAdd(&score[row + 1], s1);
            atomicAdd(&score[row + 2], s2);
            atomicAdd(&score[row + 3], s3);
        }
    }
}

// ---------------------------------------------------------------------------
// scan: p = sigmoid(score + b2, masked, + noise); att_l = p_l * prod_{i<l}(1-p_i)
// ---------------------------------------------------------------------------
__global__ __launch_bounds__(64) void scan_kernel(const float* __restrict__ score,
                                                  const int* __restrict__ mask,
                                                  const float* __restrict__ noise,
                                                  const float* __restrict__ b2p,
                                                  float* __restrict__ att) {
    int b = blockIdx.x;
    int lane = threadIdx.x;
    float b2 = b2p[0];
    int base = b * Ll + lane * 16;

    float p[16], q[16];
    float run = 1.f;
#pragma unroll
    for (int j = 0; j < 16; ++j) {
        int l = base + j;
        float s = score[l] + b2;
        if (mask[l] == 0) s = NEG_NUM;
        s += noise[l];
        float pv = 1.f / (1.f + expf(-s));
        p[j] = pv;
        run *= (1.f - pv);
        q[j] = run;
    }
    float incl = run;
#pragma unroll
    for (int off = 1; off < 64; off <<= 1) {
        float v = __shfl_up(incl, off, 64);
        if (lane >= off) incl *= v;
    }
    float excl = __shfl_up(incl, 1, 64);
    if (lane == 0) excl = 1.f;
#pragma unroll
    for (int j = 0; j < 16; ++j) {
        float P = excl * (j == 0 ? 1.f : q[j - 1]);
        att[base + j] = p[j] * P;
    }
}

// ---------------------------------------------------------------------------
// expected_ctx[b,c] = sum_l att[b,l] * ctx[b,l,c]  (fp32 ctx, float4/thread)
// ---------------------------------------------------------------------------
__global__ __launch_bounds__(256) void ectx_kernel(const float* __restrict__ ctx,
                                                   const float* __restrict__ att,
                                                   float* __restrict__ out) {
    int b = blockIdx.z;
    int c4 = threadIdx.x;                 // c = c4*4
    int l0 = blockIdx.y * 64;
    const float* cb = ctx + ((size_t)b * Ll + l0) * DC + c4 * 4;
    const float* ab = att + (size_t)b * Ll + l0;
    float a0 = 0.f, a1 = 0.f, a2 = 0.f, a3 = 0.f;
#pragma unroll 4
    for (int l = 0; l < 64; ++l) {
        float av = ab[l];
        float4 v = *(const float4*)(cb + (size_t)l * DC);
        a0 += av * v.x; a1 += av * v.y; a2 += av * v.z; a3 += av * v.w;
    }
    float* o = out + (size_t)b * DC + c4 * 4;
    atomicAdd(o + 0, a0); atomicAdd(o + 1, a1);
    atomicAdd(o + 2, a2); atomicAdd(o + 3, a3);
}

// ---------------------------------------------------------------------------
extern "C" void kernel_launch(void* const* d_in, const int* in_sizes, int n_in,
                              void* d_out, int out_size, void* d_ws, size_t ws_size,
                              hipStream_t stream) {
    const float* ctx   = (const float*)d_in[0];
    const float* query = (const float*)d_in[1];
    const int*   mask  = (const int*)d_in[2];
    const float* noise = (const float*)d_in[3];
    const float* W1    = (const float*)d_in[4];
    const float* b1    = (const float*)d_in[5];
    const float* w2    = (const float*)d_in[6];
    const float* b2    = (const float*)d_in[7];

    float* out_ctx = (float*)d_out;                 // [B, DC]
    float* out_att = (float*)d_out + Bb * DC;       // [B, L]

    char* ws = (char*)d_ws;
    float* score = (float*)ws;                                   // 131072 B
    float* qb    = (float*)(ws + 131072);                        //  65536 B
    unsigned short* w1t = (unsigned short*)(ws + 196608);        // 1 MiB
    // total scratch need ~1.25 MB

    // w1t transpose-cvt + zero score/out_ctx + qb (one kernel)
    prep_kernel<<<2432, 256, 0, stream>>>(W1, query, b1, w1t, qb, score, out_ctx);

    // fused GEMM (A global->reg, cvt in-reg; B via LDS) + tanh + w2 -> score
    gemm_fused<<<dim3((Bb * Ll) / 128, Hh / 128), 256, 0, stream>>>(ctx, w1t, qb, w2, score);

    // sigmoid/mask/noise/scan -> att (second output)
    scan_kernel<<<Bb, 64, 0, stream>>>(score, mask, noise, b2, out_att);

    // expected_ctx = att @ ctx (fp32 ctx, largely L3-resident after gemm)
    ectx_kernel<<<dim3(1, Ll / 64, Bb), 256, 0, stream>>>(ctx, out_att, out_ctx);
}

// Round 8
// 123.463 us; speedup vs baseline: 1.5518x; 1.5518x over previous
//
#include <hip/hip_runtime.h>
#include <hip/hip_bf16.h>
#include <math.h>

// Problem constants
constexpr int Bb = 32;
constexpr int Ll = 1024;
constexpr int DC = 1024;
constexpr int DQ = 1024;
constexpr int Hh = 512;
#define NEG_NUM -10000.0f

typedef __attribute__((ext_vector_type(8))) short bf16x8;
typedef __attribute__((ext_vector_type(4))) float f32x4;

#define GLOAD_LDS16(g, l)                                                  \
    __builtin_amdgcn_global_load_lds(                                      \
        (const __attribute__((address_space(1))) void*)(g),                \
        (__attribute__((address_space(3))) void*)(l), 16, 0, 0)

__device__ inline unsigned short f2bf(float f) {           // RNE f32->bf16
    unsigned int x = __float_as_uint(f);
    unsigned int r = (x + 0x7FFFu + ((x >> 16) & 1u)) >> 16;
    return (unsigned short)r;
}
__device__ inline float bfu(unsigned short u) {            // bf16 bits -> f32 (exact)
    return __uint_as_float(((unsigned int)u) << 16);
}

// SWIZZLE: all bf16 staging buffers store element (row, k) at
//   elem_addr = row*1024_or_rowstride + (k ^ ((row&7)<<3))      [16B granules]
// so global_load_lds stays a LINEAR copy and only ds_read/consumer XORs.

// ---------------------------------------------------------------------------
// prep, 2432 blocks:
//   [0,2048):    W1[:DC] (1024x512) -> w1t bf16 (512x1024 transposed, swz)
//   [2048,2176): zero out_ctx AND score (32768 floats each)
//   [2176,2432): qb[b,h] = query[b,:] @ W1[DC:,h] + b1[h]
// ---------------------------------------------------------------------------
__global__ __launch_bounds__(256) void prep_kernel(const float* __restrict__ W1,
                                                   const float* __restrict__ query,
                                                   const float* __restrict__ b1,
                                                   unsigned short* __restrict__ w1t,
                                                   float* __restrict__ qb,
                                                   float* __restrict__ score,
                                                   float* __restrict__ out_ctx) {
    __shared__ float red[4][64];
    const int bid = blockIdx.x;
    if (bid < 2048) {
        int idx = bid * 256 + threadIdx.x;   // n*1024 + k
        int n = idx >> 10, k = idx & 1023;
        int ks = k ^ ((n & 7) << 3);         // swizzled element slot
        w1t[(size_t)n * 1024 + ks] = f2bf(W1[(size_t)k * Hh + n]);
    } else if (bid < 2176) {
        int i = (bid - 2048) * 256 + threadIdx.x;
        out_ctx[i] = 0.f;
        score[i] = 0.f;
    } else {
        const int qbid = bid - 2176;          // 0..255
        const int b  = qbid >> 3;
        const int hg = qbid & 7;
        const int hl = threadIdx.x & 63;
        const int j  = threadIdx.x >> 6;
        const int h  = hg * 64 + hl;
        const float* q = query + (size_t)b * DQ + j * 256;
        const float* w = W1 + (size_t)(DC + j * 256) * Hh + h;
        float a0 = 0.f, a1 = 0.f, a2 = 0.f, a3 = 0.f;
#pragma unroll 4
        for (int c = 0; c < 256; c += 4) {
            a0 += q[c + 0] * w[(size_t)(c + 0) * Hh];
            a1 += q[c + 1] * w[(size_t)(c + 1) * Hh];
            a2 += q[c + 2] * w[(size_t)(c + 2) * Hh];
            a3 += q[c + 3] * w[(size_t)(c + 3) * Hh];
        }
        red[j][hl] = (a0 + a1) + (a2 + a3);
        __syncthreads();
        if (j == 0)
            qb[(size_t)b * Hh + h] = red[0][hl] + red[1][hl] + red[2][hl] + red[3][hl] + b1[h];
    }
}

// ---------------------------------------------------------------------------
// ctx fp32 -> bf16 (swizzled store), 8 elements/thread.
//   thread granule: row = i>>10, col_e = i&1023 (mult of 8);
//   store at col_e ^ ((row&7)<<3). Writes stay coalesced (permutation
//   within each 128B window).
// ---------------------------------------------------------------------------
__global__ __launch_bounds__(256) void cvt_ctx_kernel(const float* __restrict__ in,
                                                      unsigned short* __restrict__ out) {
    size_t i = (size_t)(blockIdx.x * 256 + threadIdx.x) * 8;
    int row = (int)(i >> 10);
    int col = (int)(i & 1023);
    float4 v0 = *(const float4*)(in + i);
    float4 v1 = *(const float4*)(in + i + 4);
    union { unsigned short us[8]; uint4 v; } o;
    o.us[0] = f2bf(v0.x); o.us[1] = f2bf(v0.y); o.us[2] = f2bf(v0.z); o.us[3] = f2bf(v0.w);
    o.us[4] = f2bf(v1.x); o.us[5] = f2bf(v1.y); o.us[6] = f2bf(v1.z); o.us[7] = f2bf(v1.w);
    *(uint4*)(out + ((size_t)row << 10) + (col ^ ((row & 7) << 3))) = o.v;
}

// ---------------------------------------------------------------------------
// MFMA GEMM + tanh + w2 reduction — m97 2-barrier structure, BK=64, swz LDS.
//   BM=128, BN=128, BK=64, 256 thr / 4 waves (2x2), acc 4x4 per wave.
//   Staging: LINEAR global_load_lds of the pre-swizzled ctxb/w1t buffers
//   (A 16KB + B 16KB per step, 4+4 issues/thread). ds_read applies
//   byte ^ ((row&7)<<4): conflict-free (2 lanes/bank). 16 steps, 32 barriers
//   (half of BK=32). FP accumulation order identical to the BK=32 version.
// ---------------------------------------------------------------------------
__global__ __launch_bounds__(256) void gemm_mfma(const unsigned short* __restrict__ ctxb,
                                                 const unsigned short* __restrict__ w1t,
                                                 const float* __restrict__ qb,
                                                 const float* __restrict__ w2,
                                                 float* __restrict__ score) {
    __shared__ unsigned short As[128 * 64];   // [m][128B k-row] = 16 KB
    __shared__ unsigned short Bs[128 * 64];   // [n][128B k-row] = 16 KB

    const int m0 = blockIdx.x * 128;
    const int n0 = blockIdx.y * 128;
    const int tid = threadIdx.x;
    const int w = tid >> 6, lane = tid & 63;
    const int wr = w >> 1, wc = w & 1;
    const int lr = lane & 15, lk = lane >> 4;

    const char* ctxB = (const char*)ctxb;
    const char* w1tB = (const char*)w1t;
    char* AsB = (char*)As;
    char* BsB = (char*)Bs;

    // staging coords: issue i -> LDS offset i*4096 + tid*16
    const int srow = tid >> 3;                 // + i*32
    const int scolb = (tid & 7) * 16;

    // fragment read XOR (row&7 == lr&7 for every frag row: 64,16 are mult of 8)
    const int x = (lr & 7) << 4;

    f32x4 acc[4][4];
#pragma unroll
    for (int mf = 0; mf < 4; ++mf)
#pragma unroll
        for (int nf = 0; nf < 4; ++nf) acc[mf][nf] = (f32x4){0.f, 0.f, 0.f, 0.f};

    for (int k0 = 0; k0 < DC; k0 += 64) {
        // ---- stage: linear copy of pre-swizzled buffers (fire-and-forget) ----
#pragma unroll
        for (int i = 0; i < 4; ++i) {
            int row = i * 32 + srow;
            GLOAD_LDS16(ctxB + (size_t)(m0 + row) * 2048 + k0 * 2 + scolb,
                        AsB + i * 4096 + tid * 16);
            GLOAD_LDS16(w1tB + (size_t)(n0 + row) * 2048 + k0 * 2 + scolb,
                        BsB + i * 4096 + tid * 16);
        }
        __syncthreads();

        // ---- compute: 2 k-halves x (8 ds_read_b128 + 16 MFMA) ----
#pragma unroll
        for (int kk = 0; kk < 2; ++kk) {
            const int colb = (kk * 64 + lk * 16) ^ x;
            bf16x8 a[4], bb[4];
#pragma unroll
            for (int mf = 0; mf < 4; ++mf)
                a[mf] = *(const bf16x8*)(AsB + (wr * 64 + mf * 16 + lr) * 128 + colb);
#pragma unroll
            for (int nf = 0; nf < 4; ++nf)
                bb[nf] = *(const bf16x8*)(BsB + (wc * 64 + nf * 16 + lr) * 128 + colb);
#pragma unroll
            for (int mf = 0; mf < 4; ++mf)
#pragma unroll
                for (int nf = 0; nf < 4; ++nf)
                    acc[mf][nf] = __builtin_amdgcn_mfma_f32_16x16x32_bf16(a[mf], bb[nf], acc[mf][nf], 0, 0, 0);
        }
        __syncthreads();
    }

    // ---- epilogue: score[row] += sum_col tanh(acc + qb[col]) * w2[col] ----
    // C/D layout: col = n0 + wc*64 + nf*16 + lr, row = m0 + wr*64 + mf*16 + lk*4 + r.
    const int bq = m0 >> 10;                     // 128 | 1024 -> one batch per block
    const float* qbb = qb + (size_t)bq * Hh;
#pragma unroll
    for (int mf = 0; mf < 4; ++mf) {
        float s0 = 0.f, s1 = 0.f, s2 = 0.f, s3 = 0.f;
#pragma unroll
        for (int nf = 0; nf < 4; ++nf) {
            int col = n0 + wc * 64 + nf * 16 + lr;
            float wv = w2[col];
            float qv = qbb[col];
            s0 += tanhf(acc[mf][nf][0] + qv) * wv;
            s1 += tanhf(acc[mf][nf][1] + qv) * wv;
            s2 += tanhf(acc[mf][nf][2] + qv) * wv;
            s3 += tanhf(acc[mf][nf][3] + qv) * wv;
        }
#pragma unroll
        for (int off = 8; off; off >>= 1) {
            s0 += __shfl_xor(s0, off, 16);
            s1 += __shfl_xor(s1, off, 16);
            s2 += __shfl_xor(s2, off, 16);
            s3 += __shfl_xor(s3, off, 16);
        }
        if (lr == 0) {
            int row = m0 + wr * 64 + mf * 16 + lk * 4;
            atomicAdd(&score[row + 0], s0);
            atomicAdd(&score[row + 1], s1);
            atomicAdd(&score[row + 2], s2);
            atomicAdd(&score[row + 3], s3);
        }
    }
}

// ---------------------------------------------------------------------------
// scan: p = sigmoid(score + b2, masked, + noise); att_l = p_l * prod_{i<l}(1-p_i)
// ---------------------------------------------------------------------------
__global__ __launch_bounds__(64) void scan_kernel(const float* __restrict__ score,
                                                  const int* __restrict__ mask,
                                                  const float* __restrict__ noise,
                                                  const float* __restrict__ b2p,
                                                  float* __restrict__ att) {
    int b = blockIdx.x;
    int lane = threadIdx.x;
    float b2 = b2p[0];
    int base = b * Ll + lane * 16;

    float p[16], q[16];
    float run = 1.f;
#pragma unroll
    for (int j = 0; j < 16; ++j) {
        int l = base + j;
        float s = score[l] + b2;
        if (mask[l] == 0) s = NEG_NUM;
        s += noise[l];
        float pv = 1.f / (1.f + expf(-s));
        p[j] = pv;
        run *= (1.f - pv);
        q[j] = run;
    }
    float incl = run;
#pragma unroll
    for (int off = 1; off < 64; off <<= 1) {
        float v = __shfl_up(incl, off, 64);
        if (lane >= off) incl *= v;
    }
    float excl = __shfl_up(incl, 1, 64);
    if (lane == 0) excl = 1.f;
#pragma unroll
    for (int j = 0; j < 16; ++j) {
        float P = excl * (j == 0 ? 1.f : q[j - 1]);
        att[base + j] = p[j] * P;
    }
}

// ---------------------------------------------------------------------------
// expected_ctx[b,c] = sum_l att[b,l] * ctx[b,l,c]  (swz bf16 ctxb, 4 c/thread)
//   swizzled read: elem slot = c ^ ((l&7)<<3); 8B loads stay aligned
//   (XOR touches elem bits 3-5 only) and wave-coalesced within 512B spans.
// ---------------------------------------------------------------------------
__global__ __launch_bounds__(256) void ectx_bf16_kernel(const unsigned short* __restrict__ ctxb,
                                                        const float* __restrict__ att,
                                                        float* __restrict__ out) {
    int b = blockIdx.z;
    int c4 = threadIdx.x;                 // c = c4*4
    int l0 = blockIdx.y * 128;
    const unsigned short* cb = ctxb + ((size_t)b * Ll + l0) * DC;
    const float* ab = att + (size_t)b * Ll + l0;
    const int c = c4 * 4;
    float a0 = 0.f, a1 = 0.f, a2 = 0.f, a3 = 0.f;
    for (int l = 0; l < 128; ++l) {
        float av = ab[l];
        int cs = c ^ ((l & 7) << 3);
        ushort4 v = *(const ushort4*)(cb + (size_t)l * DC + cs);
        a0 += av * bfu(v.x); a1 += av * bfu(v.y);
        a2 += av * bfu(v.z); a3 += av * bfu(v.w);
    }
    float* o = out + (size_t)b * DC + c;
    atomicAdd(o + 0, a0); atomicAdd(o + 1, a1);
    atomicAdd(o + 2, a2); atomicAdd(o + 3, a3);
}

// ---------------------------------------------------------------------------
extern "C" void kernel_launch(void* const* d_in, const int* in_sizes, int n_in,
                              void* d_out, int out_size, void* d_ws, size_t ws_size,
                              hipStream_t stream) {
    const float* ctx   = (const float*)d_in[0];
    const float* query = (const float*)d_in[1];
    const int*   mask  = (const int*)d_in[2];
    const float* noise = (const float*)d_in[3];
    const float* W1    = (const float*)d_in[4];
    const float* b1    = (const float*)d_in[5];
    const float* w2    = (const float*)d_in[6];
    const float* b2    = (const float*)d_in[7];

    float* out_ctx = (float*)d_out;                 // [B, DC]
    float* out_att = (float*)d_out + Bb * DC;       // [B, L]

    char* ws = (char*)d_ws;
    float* score = (float*)ws;                                   // 131072 B
    float* qb    = (float*)(ws + 131072);                        //  65536 B
    unsigned short* w1t  = (unsigned short*)(ws + 196608);       // 1 MiB
    unsigned short* ctxb = (unsigned short*)(ws + 1245184);      // 64 MiB

    // w1t transpose-cvt (swz) + zero score/out_ctx + qb (one kernel)
    prep_kernel<<<2432, 256, 0, stream>>>(W1, query, b1, w1t, qb, score, out_ctx);

    // ctx -> bf16 (swizzled store)
    cvt_ctx_kernel<<<(Bb * Ll * DC) / (256 * 8), 256, 0, stream>>>(ctx, ctxb);

    // MFMA GEMM (BK=64, conflict-free swz ds_read) + tanh + w2 -> score
    gemm_mfma<<<dim3((Bb * Ll) / 128, Hh / 128), 256, 0, stream>>>(ctxb, w1t, qb, w2, score);

    // sigmoid/mask/noise/scan -> att (second output)
    scan_kernel<<<Bb, 64, 0, stream>>>(score, mask, noise, b2, out_att);

    // expected_ctx = att @ ctx (swz bf16 ctxb, L3-resident)
    ectx_bf16_kernel<<<dim3(1, Ll / 128, Bb), 256, 0, stream>>>(ctxb, out_att, out_ctx);
}